// Round 7
// baseline (370.922 us; speedup 1.0000x reference)
//
#include <hip/hip_runtime.h>
#include <hip/hip_bf16.h>
#include <stdint.h>

// B=2, SQ=2048, SE=2048, SKV=4096, H=1024, NH=16, HD=64
// fp32 in/out; internal compute bf16 MFMA.

typedef __attribute__((ext_vector_type(8))) short short8;
typedef __attribute__((ext_vector_type(4))) float f32x4;
typedef __attribute__((ext_vector_type(4))) unsigned short us4;

// may_alias types for the P LDS handoff (written as u64, read as short8):
// without them TBAA lets the scheduler hoist the ds_read above the ds_write
// (R3 failure: absmax 2.78 with identical algorithm, only regalloc changed).
typedef __attribute__((ext_vector_type(8), may_alias)) short short8a;
typedef __attribute__((may_alias)) unsigned long long u64a;

#define MEMBAR() asm volatile("" ::: "memory")
#define DEV static __device__ __forceinline__

DEV unsigned short f2bf(float f) {
  unsigned int u = __builtin_bit_cast(unsigned int, f);
  u += 0x7fffu + ((u >> 16) & 1u);   // RNE
  return (unsigned short)(u >> 16);
}

DEV float exp2_(float x) {
#if __has_builtin(__builtin_amdgcn_exp2f)
  return __builtin_amdgcn_exp2f(x);
#else
  float r; asm("v_exp_f32 %0, %1" : "=v"(r) : "v"(x)); return r;
#endif
}

DEV unsigned int cvtpk_bf16(float lo, float hi) {
  unsigned int r;
  asm("v_cvt_pk_bf16_f32 %0, %1, %2" : "=v"(r) : "v"(lo), "v"(hi));
  return r;
}

DEV void g2lds16(const void* g, void* l) {
  __builtin_amdgcn_global_load_lds((const __attribute__((address_space(1))) void*)g,
                                   (__attribute__((address_space(3))) void*)l, 16, 0, 0);
}

// ---------- input conversion: all_hs = concat(hidden, encoder) -> bf16 ----------
__global__ __launch_bounds__(256) void convert_allhs(const float* __restrict__ hid,
                                                     const float* __restrict__ enc,
                                                     unsigned short* __restrict__ ah) {
  int idx = blockIdx.x * 256 + threadIdx.x;
  const int perB = 4096 * 256;
  int b = idx / perB, r = idx - b * perB;
  int s = r >> 8, c4 = r & 255;
  const float* srcrow = (s < 2048) ? hid + (size_t)(b * 2048 + s) * 1024
                                   : enc + (size_t)(b * 2048 + (s - 2048)) * 1024;
  f32x4 v = *(const f32x4*)(srcrow + c4 * 4);
  us4 o;
  o[0] = f2bf(v[0]); o[1] = f2bf(v[1]); o[2] = f2bf(v[2]); o[3] = f2bf(v[3]);
  *(us4*)(ah + (size_t)idx * 4) = o;
}

// ---------- mask premultiply by log2(e) ----------
__global__ __launch_bounds__(256) void premul_mask(const float* __restrict__ m,
                                                   float* __restrict__ o) {
  int i = blockIdx.x * 256 + threadIdx.x;
  o[i] = m[i] * 1.4426950408889634f;
}

// ---------- merged weight transpose: Wt[n][k] = bf16(W[k][n]) for Wq,Wk,Wv ----------
__global__ __launch_bounds__(256) void transpose_w3(const float* __restrict__ Wq,
                                                    const float* __restrict__ Wk,
                                                    const float* __restrict__ Wv,
                                                    unsigned short* __restrict__ WtBase) {
  __shared__ unsigned short t[64][65];
  const int z = blockIdx.z;
  const float* W = (z == 0) ? Wq : (z == 1) ? Wk : Wv;
  unsigned short* Wt = WtBase + (size_t)z * 1048576;
  int k0 = blockIdx.y * 64, n0 = blockIdx.x * 64;
  int tid = threadIdx.x;
#pragma unroll
  for (int rep = 0; rep < 16; rep++) {
    int idx = rep * 256 + tid;
    int kk = idx >> 6, nn = idx & 63;
    t[kk][nn] = f2bf(W[(size_t)(k0 + kk) * 1024 + n0 + nn]);
  }
  __syncthreads();
#pragma unroll
  for (int rep = 0; rep < 16; rep++) {
    int idx = rep * 256 + tid;
    int nn = idx >> 6, kk = idx & 63;
    Wt[(size_t)(n0 + nn) * 1024 + k0 + kk] = t[kk][nn];
  }
}

// ---------- merged NT GEMM: Q + K + V projections in ONE 1280-block dispatch ----------
// Tile list (after XCD swizzle): [0,256) Q, [256,768) K, [768,1280) V.
// Q/K (mode 0): D[r][c] = sum_k Wt[r][k]*AH[c][k]; out[((r>>6)*S + c)*64 + (r&63)] = (D+bias[r])*osc
// V   (mode 1): D[r][c] = sum_k AH[r][k]*WtV[c][k]; out[c*S + r] = D + bias[c]   (transposed V)
__global__ __launch_bounds__(256) void gemm_all(const unsigned short* __restrict__ WTQ,
                                                const unsigned short* __restrict__ WTK,
                                                const unsigned short* __restrict__ WTV,
                                                const unsigned short* __restrict__ AH,
                                                const float* __restrict__ bq,
                                                const float* __restrict__ bk,
                                                const float* __restrict__ bv,
                                                unsigned short* __restrict__ Qout,
                                                unsigned short* __restrict__ Kout,
                                                unsigned short* __restrict__ Vout,
                                                float qscale) {
  __shared__ unsigned short ldsA[128 * 32];
  __shared__ unsigned short ldsB[128 * 32];

  // bijective XCD chunking over 1280 tiles (1280 % 8 == 0)
  int id = blockIdx.x;
  int f2 = (id & 7) * 160 + (id >> 3);

  const unsigned short *A, *Bm;
  const float* bias;
  unsigned short* outb;
  int S, mode, r0, c0;
  float osc = 1.0f;
  if (f2 < 256) {                       // Q: c 16 x r 8 x b 2
    int t = f2;
    int b = t >> 7; t &= 127;
    c0 = (t & 15) * 128; r0 = (t >> 4) * 128;
    A = WTQ; Bm = AH + (size_t)b * 4194304; bias = bq;
    outb = Qout + (size_t)b * 2097152; S = 2048; mode = 0; osc = qscale;
  } else if (f2 < 768) {                // K: c 32 x r 8 x b 2
    int t = f2 - 256;
    int b = t >> 8; t &= 255;
    c0 = (t & 31) * 128; r0 = (t >> 5) * 128;
    A = WTK; Bm = AH + (size_t)b * 4194304; bias = bk;
    outb = Kout + (size_t)b * 4194304; S = 4096; mode = 0;
  } else {                              // V: c 8 x r 32 x b 2
    int t = f2 - 768;
    int b = t >> 8; t &= 255;
    c0 = (t & 7) * 128; r0 = (t >> 3) * 128;
    A = AH + (size_t)b * 4194304; Bm = WTV; bias = bv;
    outb = Vout + (size_t)b * 4194304; S = 4096; mode = 1;
  }

  const int tid = threadIdx.x, w = tid >> 6, l = tid & 63;
  const int wr = w >> 1, wc = w & 1;
  const int lrow = l >> 2, lk = (l & 3) * 8;
  const int lc = l & 15, g = l >> 4;

  f32x4 acc[4][4];
#pragma unroll
  for (int i = 0; i < 4; i++)
#pragma unroll
    for (int j = 0; j < 4; j++) acc[i][j] = (f32x4){0.f, 0.f, 0.f, 0.f};

  for (int k0 = 0; k0 < 1024; k0 += 32) {
#pragma unroll
    for (int t = 0; t < 2; t++) {
      const int tt = w * 2 + t;
      g2lds16(A + (size_t)(r0 + tt * 16 + lrow) * 1024 + k0 + lk, (char*)ldsA + tt * 1024);
      g2lds16(Bm + (size_t)(c0 + tt * 16 + lrow) * 1024 + k0 + lk, (char*)ldsB + tt * 1024);
    }
    __syncthreads();
    short8 af[4], bf[4];
#pragma unroll
    for (int f = 0; f < 4; f++) {
      af[f] = *(const short8*)((const char*)ldsA + (wr * 64 + f * 16 + lc) * 64 + g * 16);
      bf[f] = *(const short8*)((const char*)ldsB + (wc * 64 + f * 16 + lc) * 64 + g * 16);
    }
#pragma unroll
    for (int fr = 0; fr < 4; fr++)
#pragma unroll
      for (int fc = 0; fc < 4; fc++)
        acc[fr][fc] = __builtin_amdgcn_mfma_f32_16x16x32_bf16(af[fr], bf[fc], acc[fr][fc], 0, 0, 0);
    __syncthreads();
  }

#pragma unroll
  for (int fr = 0; fr < 4; fr++) {
    int rb = r0 + wr * 64 + fr * 16 + g * 4;
    float bv4[4];
    if (mode == 0) {
#pragma unroll
      for (int i = 0; i < 4; i++) bv4[i] = bias[rb + i];
    }
#pragma unroll
    for (int fc = 0; fc < 4; fc++) {
      int c = c0 + wc * 64 + fc * 16 + lc;
      float bc = (mode == 0) ? 0.f : bias[c];
      us4 pk;
#pragma unroll
      for (int i = 0; i < 4; i++) {
        float v = (acc[fr][fc][i] + (mode == 0 ? bv4[i] : bc)) * osc;
        pk[i] = f2bf(v);
      }
      size_t addr;
      if (mode == 0) addr = ((size_t)(rb >> 6) * S + c) * 64 + (rb & 63);
      else           addr = (size_t)c * S + rb;
      *(us4*)(outb + addr) = pk;
    }
  }
}

// ---------- flash attention v7: K-only LDS dbuf (24KB), V direct from global ----------
// Q[b][h][sq][d] (pre-scaled by 0.125*log2e), K[b][h][skv][d], Vt[b][h][d][skv] (bf16);
// mask2 = mask*log2e fp32; out fp32 [B][SQ][H].
// R6 was LDS-capped at 3 blocks/CU (40960B). V tile is L2-resident (T1 swizzle keeps
// ~2 heads per XCD), so V staging was pure overhead (common-mistake #7): read V
// fragments straight from global. LDS -> 24576B -> 6 blocks fit; VGPR (~110 with early
// V frags) caps waves at 4/SIMD -> 50% occupancy, and the tile barrier drains half the DMA.
__global__ __launch_bounds__(256) void attn_kernel(const unsigned short* __restrict__ Q,
                                                   const unsigned short* __restrict__ K,
                                                   const unsigned short* __restrict__ Vt,
                                                   const float* __restrict__ mask2,
                                                   float* __restrict__ out) {
  __shared__ __align__(16) char ldsK[2][8192];     // K tile 64 rows x 128B, double-buffered
  __shared__ unsigned short plds[4096];            // per-wave P^T staging (2KB each)

  // XCD-chunked swizzle (T1)
  int flat = blockIdx.x + 32 * (blockIdx.y + 16 * blockIdx.z);   // 0..1023
  int xc = flat & 7, tt = flat >> 3;                             // tt: 0..127
  int f2 = xc * 64 + (tt & 63) + (tt >> 6) * 512;
  const int qt = f2 & 31, h = (f2 >> 5) & 15, b = f2 >> 9;

  const int tid = threadIdx.x, w = tid >> 6, l = tid & 63;
  const int lc = l & 15, g = l >> 4;

  const unsigned short* Qb = Q + ((size_t)(b * 16 + h) * 2048) * 64;
  const unsigned short* Kb = K + ((size_t)(b * 16 + h) * 4096) * 64;
  const unsigned short* Vb = Vt + ((size_t)(b * 16 + h) * 64) * 4096;
  const float* mk = mask2 + (size_t)b * 4096;
  const int sq0 = qt * 64 + w * 16;

  // staging lane geometry: call covers 8 rows x 128B; lane l -> row +(l>>3), chunk (l&7)^(row&7)
  const int srow = l >> 3;
  const int schunk = (l & 7) ^ srow;

  short8 qf[2];
#pragma unroll
  for (int hh = 0; hh < 2; hh++)
    qf[hh] = *(const short8*)(Qb + (size_t)(sq0 + lc) * 64 + hh * 32 + g * 8);

  // ones fragment (bf16 1.0 x8) for the ls-sum MFMA
  short8 ones;
#pragma unroll
  for (int i = 0; i < 8; i++) ones[i] = (short)0x3f80;

  f32x4 ctx[4];
#pragma unroll
  for (int df = 0; df < 4; df++) ctx[df] = (f32x4){0.f, 0.f, 0.f, 0.f};
  f32x4 lsacc = (f32x4){0.f, 0.f, 0.f, 0.f};

  char* pwave = (char*)plds + w * 2048;
  const int swz = (lc & 7) << 4;

  // ---- stage K tile 0 ----
  {
#pragma unroll
    for (int c = 0; c < 2; c++) {
      int call = w * 2 + c;              // 0..7, 1KB each = 8KB
      int r = call * 8 + srow;
      g2lds16(Kb + (size_t)r * 64 + schunk * 8, ldsK[0] + call * 1024);
    }
  }
  __syncthreads();

  int bf = 0;
  for (int t = 0; t < 64; t++) {
    const int s0 = t * 64;

    // ---- stage K(t+1) into the other buffer (DMA overlaps compute below) ----
    if (t < 63) {
#pragma unroll
      for (int c = 0; c < 2; c++) {
        int call = w * 2 + c;
        int r = call * 8 + srow;
        g2lds16(Kb + (size_t)(s0 + 64 + r) * 64 + schunk * 8, ldsK[bf ^ 1] + call * 1024);
      }
    }

    // ---- V fragments direct from global (L2-resident), issued early ----
    short8 vf[4][2];
#pragma unroll
    for (int df = 0; df < 4; df++)
#pragma unroll
      for (int kk = 0; kk < 2; kk++)
        vf[df][kk] = *(const short8*)(Vb + (size_t)(df * 16 + lc) * 4096 + s0 + kk * 32 + g * 8);

    // mask for this tile -> becomes the MFMA C-init (free add)
    f32x4 mvv[4];
#pragma unroll
    for (int f = 0; f < 4; f++)
      mvv[f] = *(const f32x4*)(mk + s0 + f * 16 + g * 4);

    const char* kb = ldsK[bf];

    // ---- QK^T with C = mask; then P = exp2(sc), packed to LDS ----
#pragma unroll
    for (int f = 0; f < 4; f++) {
      short8 k0 = *(const short8*)(kb + (f * 16 + lc) * 128 + ((g ^ (lc & 7)) << 4));
      short8 k1 = *(const short8*)(kb + (f * 16 + lc) * 128 + (((4 + g) ^ (lc & 7)) << 4));
      f32x4 z = __builtin_amdgcn_mfma_f32_16x16x32_bf16(k0, qf[0], mvv[f], 0, 0, 0);
      z = __builtin_amdgcn_mfma_f32_16x16x32_bf16(k1, qf[1], z, 0, 0, 0);
      unsigned int lo = cvtpk_bf16(exp2_(z[0]), exp2_(z[1]));
      unsigned int hi = cvtpk_bf16(exp2_(z[2]), exp2_(z[3]));
      int base = lc * 128 + f * 32 + g * 8;
      *(u64a*)(pwave + (base ^ swz)) = ((unsigned long long)hi << 32) | lo;
    }

    MEMBAR();  // P writes ordered before the pfrag reads below

    // ---- PV: ctx^T += V^T * P^T ; ls += ones * P^T ----
    short8 pfrag[2];
#pragma unroll
    for (int kk = 0; kk < 2; kk++)
      pfrag[kk] = (short8)*(const short8a*)(pwave + ((lc * 128 + kk * 64 + g * 16) ^ swz));
#pragma unroll
    for (int df = 0; df < 4; df++) {
      ctx[df] = __builtin_amdgcn_mfma_f32_16x16x32_bf16(vf[df][0], pfrag[0], ctx[df], 0, 0, 0);
      ctx[df] = __builtin_amdgcn_mfma_f32_16x16x32_bf16(vf[df][1], pfrag[1], ctx[df], 0, 0, 0);
    }
    lsacc = __builtin_amdgcn_mfma_f32_16x16x32_bf16(ones, pfrag[0], lsacc, 0, 0, 0);
    lsacc = __builtin_amdgcn_mfma_f32_16x16x32_bf16(ones, pfrag[1], lsacc, 0, 0, 0);

    __syncthreads();   // drains the K(t+1) DMA; waves done reading ldsK[bf]
    bf ^= 1;
  }

  // ---- epilogue: all 4 lsacc elements hold the same column-sum ----
  float inv = 1.f / lsacc[0];
  size_t row = (size_t)(b * 2048 + sq0 + lc);
#pragma unroll
  for (int df = 0; df < 4; df++) {
    f32x4 o = ctx[df] * inv;
    *(f32x4*)(out + row * 1024 + h * 64 + df * 16 + g * 4) = o;
  }
}

// ---------- launcher ----------
extern "C" void kernel_launch(void* const* d_in, const int* in_sizes, int n_in,
                              void* d_out, int out_size, void* d_ws, size_t ws_size,
                              hipStream_t stream) {
  const float* hid = (const float*)d_in[0];
  const float* enc = (const float*)d_in[1];
  const float* mask = (const float*)d_in[2];
  const float* Wq = (const float*)d_in[3];
  const float* bq = (const float*)d_in[4];
  const float* Wk = (const float*)d_in[5];
  const float* bk = (const float*)d_in[6];
  const float* Wv = (const float*)d_in[7];
  const float* bv = (const float*)d_in[8];

  unsigned short* ws = (unsigned short*)d_ws;
  unsigned short* WTQ = ws;                    // 1M elems (WTQ/WTK/WTV contiguous)
  unsigned short* WTK = ws + 1048576;          // 1M
  unsigned short* WTV = ws + 2097152;          // 1M
  unsigned short* AH  = ws + 3145728;          // 8M  [B][4096][1024]
  unsigned short* Qb  = ws + 11534336;         // 4M  [B][16][2048][64]
  unsigned short* Kb  = ws + 15728640;         // 8M  [B][16][4096][64]
  unsigned short* VT  = ws + 24117248;         // 8M  [B][16][64][4096]
  float* mask2 = (float*)(ws + 32505856);      // 8192 fp32

  const float QSCALE = 0.18033688011112042f;   // 0.125 * log2(e), folded into Q projection

  convert_allhs<<<8192, 256, 0, stream>>>(hid, enc, AH);
  premul_mask<<<32, 256, 0, stream>>>(mask, mask2);
  transpose_w3<<<dim3(16, 16, 3), 256, 0, stream>>>(Wq, Wk, Wv, WTQ);

  gemm_all<<<1280, 256, 0, stream>>>(WTQ, WTK, WTV, AH, bq, bk, bv, Qb, Kb, VT, QSCALE);

  attn_kernel<<<dim3(32, 16, 2), 256, 0, stream>>>(Qb, Kb, VT, mask2, (float*)d_out);
}

// Round 8
// 196.651 us; speedup vs baseline: 1.8862x; 1.8862x over previous
//
#include <hip/hip_runtime.h>
#include <hip/hip_bf16.h>
#include <stdint.h>

// B=2, SQ=2048, SE=2048, SKV=4096, H=1024, NH=16, HD=64
// fp32 in/out; internal compute bf16 MFMA.

typedef __attribute__((ext_vector_type(8))) short short8;
typedef __attribute__((ext_vector_type(4))) float f32x4;
typedef __attribute__((ext_vector_type(4))) unsigned short us4;

// may_alias types for LDS handoffs (written as one type, read as another):
// without them TBAA lets the scheduler hoist ds_reads above ds_writes
// (R3 failure: absmax 2.78 with identical algorithm, only regalloc changed).
typedef __attribute__((ext_vector_type(8), may_alias)) short short8a;
typedef __attribute__((may_alias)) unsigned long long u64a;

#define MEMBAR() asm volatile("" ::: "memory")
#define DEV static __device__ __forceinline__

DEV unsigned short f2bf(float f) {
  unsigned int u = __builtin_bit_cast(unsigned int, f);
  u += 0x7fffu + ((u >> 16) & 1u);   // RNE
  return (unsigned short)(u >> 16);
}

DEV float exp2_(float x) {
#if __has_builtin(__builtin_amdgcn_exp2f)
  return __builtin_amdgcn_exp2f(x);
#else
  float r; asm("v_exp_f32 %0, %1" : "=v"(r) : "v"(x)); return r;
#endif
}

DEV unsigned int cvtpk_bf16(float lo, float hi) {
  unsigned int r;
  asm("v_cvt_pk_bf16_f32 %0, %1, %2" : "=v"(r) : "v"(lo), "v"(hi));
  return r;
}

DEV void g2lds16(const void* g, void* l) {
  __builtin_amdgcn_global_load_lds((const __attribute__((address_space(1))) void*)g,
                                   (__attribute__((address_space(3))) void*)l, 16, 0, 0);
}

// ---------- input conversion: all_hs = concat(hidden, encoder) -> bf16 ----------
__global__ __launch_bounds__(256) void convert_allhs(const float* __restrict__ hid,
                                                     const float* __restrict__ enc,
                                                     unsigned short* __restrict__ ah) {
  int idx = blockIdx.x * 256 + threadIdx.x;
  const int perB = 4096 * 256;
  int b = idx / perB, r = idx - b * perB;
  int s = r >> 8, c4 = r & 255;
  const float* srcrow = (s < 2048) ? hid + (size_t)(b * 2048 + s) * 1024
                                   : enc + (size_t)(b * 2048 + (s - 2048)) * 1024;
  f32x4 v = *(const f32x4*)(srcrow + c4 * 4);
  us4 o;
  o[0] = f2bf(v[0]); o[1] = f2bf(v[1]); o[2] = f2bf(v[2]); o[3] = f2bf(v[3]);
  *(us4*)(ah + (size_t)idx * 4) = o;
}

// ---------- mask premultiply by log2(e) ----------
__global__ __launch_bounds__(256) void premul_mask(const float* __restrict__ m,
                                                   float* __restrict__ o) {
  int i = blockIdx.x * 256 + threadIdx.x;
  o[i] = m[i] * 1.4426950408889634f;
}

// ---------- merged weight transpose: Wt[n][k] = bf16(W[k][n]) for Wq,Wk,Wv ----------
__global__ __launch_bounds__(256) void transpose_w3(const float* __restrict__ Wq,
                                                    const float* __restrict__ Wk,
                                                    const float* __restrict__ Wv,
                                                    unsigned short* __restrict__ WtBase) {
  __shared__ unsigned short t[64][65];
  const int z = blockIdx.z;
  const float* W = (z == 0) ? Wq : (z == 1) ? Wk : Wv;
  unsigned short* Wt = WtBase + (size_t)z * 1048576;
  int k0 = blockIdx.y * 64, n0 = blockIdx.x * 64;
  int tid = threadIdx.x;
#pragma unroll
  for (int rep = 0; rep < 16; rep++) {
    int idx = rep * 256 + tid;
    int kk = idx >> 6, nn = idx & 63;
    t[kk][nn] = f2bf(W[(size_t)(k0 + kk) * 1024 + n0 + nn]);
  }
  __syncthreads();
#pragma unroll
  for (int rep = 0; rep < 16; rep++) {
    int idx = rep * 256 + tid;
    int nn = idx >> 6, kk = idx & 63;
    Wt[(size_t)(n0 + nn) * 1024 + k0 + kk] = t[kk][nn];
  }
}

// ---------- merged NT GEMM: Q + K + V projections in ONE 1280-block dispatch ----------
__global__ __launch_bounds__(256) void gemm_all(const unsigned short* __restrict__ WTQ,
                                                const unsigned short* __restrict__ WTK,
                                                const unsigned short* __restrict__ WTV,
                                                const unsigned short* __restrict__ AH,
                                                const float* __restrict__ bq,
                                                const float* __restrict__ bk,
                                                const float* __restrict__ bv,
                                                unsigned short* __restrict__ Qout,
                                                unsigned short* __restrict__ Kout,
                                                unsigned short* __restrict__ Vout,
                                                float qscale) {
  __shared__ unsigned short ldsA[128 * 32];
  __shared__ unsigned short ldsB[128 * 32];

  // bijective XCD chunking over 1280 tiles (1280 % 8 == 0)
  int id = blockIdx.x;
  int f2 = (id & 7) * 160 + (id >> 3);

  const unsigned short *A, *Bm;
  const float* bias;
  unsigned short* outb;
  int S, mode, r0, c0;
  float osc = 1.0f;
  if (f2 < 256) {                       // Q: c 16 x r 8 x b 2
    int t = f2;
    int b = t >> 7; t &= 127;
    c0 = (t & 15) * 128; r0 = (t >> 4) * 128;
    A = WTQ; Bm = AH + (size_t)b * 4194304; bias = bq;
    outb = Qout + (size_t)b * 2097152; S = 2048; mode = 0; osc = qscale;
  } else if (f2 < 768) {                // K: c 32 x r 8 x b 2
    int t = f2 - 256;
    int b = t >> 8; t &= 255;
    c0 = (t & 31) * 128; r0 = (t >> 5) * 128;
    A = WTK; Bm = AH + (size_t)b * 4194304; bias = bk;
    outb = Kout + (size_t)b * 4194304; S = 4096; mode = 0;
  } else {                              // V: c 8 x r 32 x b 2
    int t = f2 - 768;
    int b = t >> 8; t &= 255;
    c0 = (t & 7) * 128; r0 = (t >> 3) * 128;
    A = AH + (size_t)b * 4194304; Bm = WTV; bias = bv;
    outb = Vout + (size_t)b * 4194304; S = 4096; mode = 1;
  }

  const int tid = threadIdx.x, w = tid >> 6, l = tid & 63;
  const int wr = w >> 1, wc = w & 1;
  const int lrow = l >> 2, lk = (l & 3) * 8;
  const int lc = l & 15, g = l >> 4;

  f32x4 acc[4][4];
#pragma unroll
  for (int i = 0; i < 4; i++)
#pragma unroll
    for (int j = 0; j < 4; j++) acc[i][j] = (f32x4){0.f, 0.f, 0.f, 0.f};

  for (int k0 = 0; k0 < 1024; k0 += 32) {
#pragma unroll
    for (int t = 0; t < 2; t++) {
      const int tt = w * 2 + t;
      g2lds16(A + (size_t)(r0 + tt * 16 + lrow) * 1024 + k0 + lk, (char*)ldsA + tt * 1024);
      g2lds16(Bm + (size_t)(c0 + tt * 16 + lrow) * 1024 + k0 + lk, (char*)ldsB + tt * 1024);
    }
    __syncthreads();
    short8 af[4], bf[4];
#pragma unroll
    for (int f = 0; f < 4; f++) {
      af[f] = *(const short8*)((const char*)ldsA + (wr * 64 + f * 16 + lc) * 64 + g * 16);
      bf[f] = *(const short8*)((const char*)ldsB + (wc * 64 + f * 16 + lc) * 64 + g * 16);
    }
#pragma unroll
    for (int fr = 0; fr < 4; fr++)
#pragma unroll
      for (int fc = 0; fc < 4; fc++)
        acc[fr][fc] = __builtin_amdgcn_mfma_f32_16x16x32_bf16(af[fr], bf[fc], acc[fr][fc], 0, 0, 0);
    __syncthreads();
  }

#pragma unroll
  for (int fr = 0; fr < 4; fr++) {
    int rb = r0 + wr * 64 + fr * 16 + g * 4;
    float bv4[4];
    if (mode == 0) {
#pragma unroll
      for (int i = 0; i < 4; i++) bv4[i] = bias[rb + i];
    }
#pragma unroll
    for (int fc = 0; fc < 4; fc++) {
      int c = c0 + wc * 64 + fc * 16 + lc;
      float bc = (mode == 0) ? 0.f : bias[c];
      us4 pk;
#pragma unroll
      for (int i = 0; i < 4; i++) {
        float v = (acc[fr][fc][i] + (mode == 0 ? bv4[i] : bc)) * osc;
        pk[i] = f2bf(v);
      }
      size_t addr;
      if (mode == 0) addr = ((size_t)(rb >> 6) * S + c) * 64 + (rb & 63);
      else           addr = (size_t)c * S + rb;
      *(us4*)(outb + addr) = pk;
    }
  }
}

// ---------- flash attention v8: reg-staged KV (T14), single LDS buffer, 24.5KB ----------
// Q[b][h][sq][d] (pre-scaled by 0.125*log2e), K[b][h][skv][d], Vt[b][h][d][skv] (bf16);
// mask2 = mask*log2e fp32; out fp32 [B][SQ][H].
// R7 lesson: V global loads issued AFTER the K-DMA serialize on vmcnt (in-order counter)
// -> every tile paid full prefetch latency. R8: stage K AND V tile t+1 via VGPRs
// (4x global_load_dwordx4/thread, issued AFTER the mask loads so the mask wait is
// vmcnt(8) and leaves the prefetch in flight), compute tile t from single-buffered LDS,
// then barrier -> ds_write regs -> barrier. The vmcnt(0) wait lands after the whole
// compute phase. LDS 24576B (was 40960): no LDS occupancy cap.
__global__ __launch_bounds__(256) void attn_kernel(const unsigned short* __restrict__ Q,
                                                   const unsigned short* __restrict__ K,
                                                   const unsigned short* __restrict__ Vt,
                                                   const float* __restrict__ mask2,
                                                   float* __restrict__ out) {
  __shared__ __align__(16) char ldsKV[16384];      // K tile 8KB @0, V tile 8KB @8192
  __shared__ unsigned short plds[4096];            // per-wave P^T staging (2KB each)
  char* ldsK = ldsKV;
  char* ldsV = ldsKV + 8192;

  // XCD-chunked swizzle (T1)
  int flat = blockIdx.x + 32 * (blockIdx.y + 16 * blockIdx.z);   // 0..1023
  int xc = flat & 7, tt = flat >> 3;                             // tt: 0..127
  int f2 = xc * 64 + (tt & 63) + (tt >> 6) * 512;
  const int qt = f2 & 31, h = (f2 >> 5) & 15, b = f2 >> 9;

  const int tid = threadIdx.x, w = tid >> 6, l = tid & 63;
  const int lc = l & 15, g = l >> 4;

  const unsigned short* Qb = Q + ((size_t)(b * 16 + h) * 2048) * 64;
  const unsigned short* Kb = K + ((size_t)(b * 16 + h) * 4096) * 64;
  const unsigned short* Vb = Vt + ((size_t)(b * 16 + h) * 64) * 4096;
  const float* mk = mask2 + (size_t)b * 4096;
  const int sq0 = qt * 64 + w * 16;

  // staging lane geometry: call covers 8 rows x 128B; lane l -> row +(l>>3),
  // global chunk (l&7)^(row&7) (pre-swizzle on the READ side; LDS write is linear,
  // so LDS row r slot j holds global chunk j^(r&7) -- same layout as R6's DMA version)
  const int srow = l >> 3;
  const int schunk = (l & 7) ^ srow;

  short8 qf[2];
#pragma unroll
  for (int hh = 0; hh < 2; hh++)
    qf[hh] = *(const short8*)(Qb + (size_t)(sq0 + lc) * 64 + hh * 32 + g * 8);

  // ones fragment (bf16 1.0 x8) for the ls-sum MFMA
  short8 ones;
#pragma unroll
  for (int i = 0; i < 8; i++) ones[i] = (short)0x3f80;

  f32x4 ctx[4];
#pragma unroll
  for (int df = 0; df < 4; df++) ctx[df] = (f32x4){0.f, 0.f, 0.f, 0.f};
  f32x4 lsacc = (f32x4){0.f, 0.f, 0.f, 0.f};

  char* pwave = (char*)plds + w * 2048;
  const int swz = (lc & 7) << 4;

  // ---- stage tile 0 via regs ----
  {
    short8 kreg[2], vreg[2];
#pragma unroll
    for (int c = 0; c < 2; c++) {
      int call = w * 2 + c;
      int r = call * 8 + srow;
      kreg[c] = *(const short8*)(Kb + (size_t)r * 64 + schunk * 8);
      vreg[c] = *(const short8*)(Vb + (size_t)r * 4096 + schunk * 8);
    }
#pragma unroll
    for (int c = 0; c < 2; c++) {
      int call = w * 2 + c;
      *(short8a*)(ldsK + call * 1024 + l * 16) = kreg[c];
      *(short8a*)(ldsV + call * 1024 + l * 16) = vreg[c];
    }
  }
  __syncthreads();

  for (int t = 0; t < 64; t++) {
    const int s0 = t * 64;

    // mask loads FIRST (oldest vmcnt slots): their wait is vmcnt(8), leaving the
    // prefetch below in flight (issue order matters -- R7 lesson).
    f32x4 mvv[4];
#pragma unroll
    for (int f = 0; f < 4; f++)
      mvv[f] = *(const f32x4*)(mk + s0 + f * 16 + g * 4);

    // ---- issue reg-prefetch of tile t+1 (lands during compute below) ----
    short8 kreg[2], vreg[2];
    if (t < 63) {
#pragma unroll
      for (int c = 0; c < 2; c++) {
        int call = w * 2 + c;
        int r = call * 8 + srow;
        kreg[c] = *(const short8*)(Kb + (size_t)(s0 + 64 + r) * 64 + schunk * 8);
        vreg[c] = *(const short8*)(Vb + (size_t)r * 4096 + (s0 + 64) + schunk * 8);
      }
    }

    // ---- QK^T with C = mask; then P = exp2(sc), packed to LDS ----
#pragma unroll
    for (int f = 0; f < 4; f++) {
      short8 k0 = *(const short8*)(ldsK + (f * 16 + lc) * 128 + ((g ^ (lc & 7)) << 4));
      short8 k1 = *(const short8*)(ldsK + (f * 16 + lc) * 128 + (((4 + g) ^ (lc & 7)) << 4));
      f32x4 z = __builtin_amdgcn_mfma_f32_16x16x32_bf16(k0, qf[0], mvv[f], 0, 0, 0);
      z = __builtin_amdgcn_mfma_f32_16x16x32_bf16(k1, qf[1], z, 0, 0, 0);
      unsigned int lo = cvtpk_bf16(exp2_(z[0]), exp2_(z[1]));
      unsigned int hi = cvtpk_bf16(exp2_(z[2]), exp2_(z[3]));
      int base = lc * 128 + f * 32 + g * 8;
      *(u64a*)(pwave + (base ^ swz)) = ((unsigned long long)hi << 32) | lo;
    }

    MEMBAR();  // P writes ordered before the pfrag reads below

    // ---- PV: ctx^T += V^T * P^T ; ls += ones * P^T ----
    short8 pfrag[2];
#pragma unroll
    for (int kk = 0; kk < 2; kk++)
      pfrag[kk] = (short8)*(const short8a*)(pwave + ((lc * 128 + kk * 64 + g * 16) ^ swz));
#pragma unroll
    for (int df = 0; df < 4; df++) {
      short8 v0 = *(const short8*)(ldsV + (df * 16 + lc) * 128 + ((g ^ (lc & 7)) << 4));
      short8 v1 = *(const short8*)(ldsV + (df * 16 + lc) * 128 + (((4 + g) ^ (lc & 7)) << 4));
      ctx[df] = __builtin_amdgcn_mfma_f32_16x16x32_bf16(v0, pfrag[0], ctx[df], 0, 0, 0);
      ctx[df] = __builtin_amdgcn_mfma_f32_16x16x32_bf16(v1, pfrag[1], ctx[df], 0, 0, 0);
    }
    lsacc = __builtin_amdgcn_mfma_f32_16x16x32_bf16(ones, pfrag[0], lsacc, 0, 0, 0);
    lsacc = __builtin_amdgcn_mfma_f32_16x16x32_bf16(ones, pfrag[1], lsacc, 0, 0, 0);

    __syncthreads();   // all waves done reading LDS tile t (drains prefetch too)

    // ---- write tile t+1 into LDS (vmcnt wait here, after full compute cover) ----
    if (t < 63) {
#pragma unroll
      for (int c = 0; c < 2; c++) {
        int call = w * 2 + c;
        *(short8a*)(ldsK + call * 1024 + l * 16) = kreg[c];
        *(short8a*)(ldsV + call * 1024 + l * 16) = vreg[c];
      }
      __syncthreads();  // tile t+1 visible to all waves
    }
  }

  // ---- epilogue: all 4 lsacc elements hold the same column-sum ----
  float inv = 1.f / lsacc[0];
  size_t row = (size_t)(b * 2048 + sq0 + lc);
#pragma unroll
  for (int df = 0; df < 4; df++) {
    f32x4 o = ctx[df] * inv;
    *(f32x4*)(out + row * 1024 + h * 64 + df * 16 + g * 4) = o;
  }
}

// ---------- launcher ----------
extern "C" void kernel_launch(void* const* d_in, const int* in_sizes, int n_in,
                              void* d_out, int out_size, void* d_ws, size_t ws_size,
                              hipStream_t stream) {
  const float* hid = (const float*)d_in[0];
  const float* enc = (const float*)d_in[1];
  const float* mask = (const float*)d_in[2];
  const float* Wq = (const float*)d_in[3];
  const float* bq = (const float*)d_in[4];
  const float* Wk = (const float*)d_in[5];
  const float* bk = (const float*)d_in[6];
  const float* Wv = (const float*)d_in[7];
  const float* bv = (const float*)d_in[8];

  unsigned short* ws = (unsigned short*)d_ws;
  unsigned short* WTQ = ws;                    // 1M elems (WTQ/WTK/WTV contiguous)
  unsigned short* WTK = ws + 1048576;          // 1M
  unsigned short* WTV = ws + 2097152;          // 1M
  unsigned short* AH  = ws + 3145728;          // 8M  [B][4096][1024]
  unsigned short* Qb  = ws + 11534336;         // 4M  [B][16][2048][64]
  unsigned short* Kb  = ws + 15728640;         // 8M  [B][16][4096][64]
  unsigned short* VT  = ws + 24117248;         // 8M  [B][16][64][4096]
  float* mask2 = (float*)(ws + 32505856);      // 8192 fp32

  const float QSCALE = 0.18033688011112042f;   // 0.125 * log2(e), folded into Q projection

  convert_allhs<<<8192, 256, 0, stream>>>(hid, enc, AH);
  premul_mask<<<32, 256, 0, stream>>>(mask, mask2);
  transpose_w3<<<dim3(16, 16, 3), 256, 0, stream>>>(Wq, Wk, Wv, WTQ);

  gemm_all<<<1280, 256, 0, stream>>>(WTQ, WTK, WTV, AH, bq, bk, bv, Qb, Kb, VT, QSCALE);

  attn_kernel<<<dim3(32, 16, 2), 256, 0, stream>>>(Qb, Kb, VT, mask2, (float*)d_out);
}